// Round 8
// baseline (202.777 us; speedup 1.0000x reference)
//
#include <hip/hip_runtime.h>
#include <stdint.h>

#define Bb 8
#define Dd 256
#define Ll 4096
#define Kk 4096
#define Nn (Bb * Ll)          // 32768 rows
#define OUT0 (Bb * Dd * Ll)   // 8388608

typedef int    int4v   __attribute__((ext_vector_type(4)));
typedef int    int8v   __attribute__((ext_vector_type(8)));
typedef float  floatx4 __attribute__((ext_vector_type(4)));

#define SCALE1 0x7F7F7F7F     // E8M0 exp=127 -> x1.0 for every 32-elem block

union V8 { int8v v; int4v h[2]; };

__device__ __forceinline__ void async_load16(const void* g, void* l) {
    __builtin_amdgcn_global_load_lds((const __attribute__((address_space(1))) void*)g,
                                     (__attribute__((address_space(3))) void*)l, 16, 0, 0);
}

// ---------------------------------------------------------------- kernel 1
// normalize codebook rows -> fp8 (x16), emit ||w_k|| for the loss formula;
// block 0 zeroes counts + lossacc + done.
__global__ void k_prep(const float* __restrict__ w, unsigned char* __restrict__ wn,
                       float* __restrict__ wnorm, int* __restrict__ counts) {
    int blk = blockIdx.x, tid = threadIdx.x;
    if (blk == 0)
        for (int i = tid; i < Kk + 2; i += 256) counts[i] = 0;
    int row  = blk * 4 + (tid >> 6);
    int lane = tid & 63;
    float4 v = ((const float4*)(w + (size_t)row * Dd))[lane];
    float ss = v.x*v.x + v.y*v.y + v.z*v.z + v.w*v.w;
#pragma unroll
    for (int m = 1; m < 64; m <<= 1) ss += __shfl_xor(ss, m, 64);
    float nrm = sqrtf(ss);
    float s = 16.0f / fmaxf(nrm, 1e-12f);
    int p = __builtin_amdgcn_cvt_pk_fp8_f32(v.x * s, v.y * s, 0, false);
    p     = __builtin_amdgcn_cvt_pk_fp8_f32(v.z * s, v.w * s, p, true);
    ((int*)(wn + (size_t)row * Dd))[lane] = p;
    if (lane == 0) wnorm[row] = nrm;
}

// ---------------------------------------------------------------- kernel 2
// Fused: transpose+fp8(x) -> GEMM argmax over all 4096 cols -> histogram +
// closed-form loss (no x re-read) -> scatter w[idx] into out -> finale.
// 512 blocks x 512 thr; block = 64 rows. LDS ~50KB -> 2-3 blocks/CU.
// Wave tile 16r x 32c (wm=wv>>1 row-group, wn=wv&1 col-half of 64-col tile).
__global__ __launch_bounds__(512, 4) void k_main(
        const float* __restrict__ x, const unsigned char* __restrict__ Wn,
        const float* __restrict__ wnorm, const float* __restrict__ w,
        float* __restrict__ out, int* __restrict__ counts) {
    __shared__ __align__(16) unsigned char smem[51200];
    unsigned char* As  = smem;                    // 16 KB [64 l][256B swz]
    unsigned char* Bs0 = smem + 16384;            // 16 KB
    unsigned char* Bs1 = smem + 32768;            // 16 KB
    unsigned int (*red)[2] = (unsigned int (*)[2])(smem + 49152);   // 64x2
    int*   kidx  = (int*)(smem + 49664);          // 64
    float* wsumS = (float*)(smem + 49920);        // 8
    int*   lastp = (int*)(smem + 49952);
    float* wt = (float*)smem;                     // scatter reuse: 32*260*4 = 33280

    float* lossacc = (float*)(counts + Kk);
    int*   done    = counts + Kk + 1;

    int bm = blockIdx.x;
    int tid = threadIdx.x, lane = tid & 63, wv = tid >> 6;
    int wm = wv >> 1, wn = wv & 1;
    int l15 = lane & 15, l4 = lane >> 4;

    // B DMA maps: 64-col tile = 1024 16B chunks, 2 per thread
    int goff[2], loff[2];
#pragma unroll
    for (int j = 0; j < 2; ++j) {
        int q = j * 512 + tid;
        int col = q >> 4, p = q & 15;
        goff[j] = col * 256 + ((p ^ (col & 15)) << 4);
        loff[j] = q * 16;
    }
    // prologue DMA: tile 0 -> Bs0 (overlaps transpose)
    async_load16(Wn + goff[0], Bs0 + loff[0]);
    async_load16(Wn + goff[1], Bs0 + loff[1]);

    // ---- transpose x slab [256 d][64 l] -> As fp8 (swz), accumulate sum(x^2)
    int b = bm >> 6, l0 = (bm & 63) * 64;
    const float* xs = x + (size_t)b * Dd * Ll + l0;
    int lg = tid & 15, dgr = tid >> 4;            // 16 l-quads x 32 d-quads
    float xs2 = 0.f;
#pragma unroll
    for (int i = 0; i < 2; ++i) {
        int d0 = dgr * 4 + i * 128;
        const float* s0 = xs + (size_t)d0 * Ll + lg * 4;
        float4 f0 = *(const float4*)(s0);
        float4 f1 = *(const float4*)(s0 + Ll);
        float4 f2 = *(const float4*)(s0 + 2 * (size_t)Ll);
        float4 f3 = *(const float4*)(s0 + 3 * (size_t)Ll);
        xs2 += f0.x*f0.x + f0.y*f0.y + f0.z*f0.z + f0.w*f0.w
             + f1.x*f1.x + f1.y*f1.y + f1.z*f1.z + f1.w*f1.w
             + f2.x*f2.x + f2.y*f2.y + f2.z*f2.z + f2.w*f2.w
             + f3.x*f3.x + f3.y*f3.y + f3.z*f3.z + f3.w*f3.w;
#pragma unroll
        for (int jl = 0; jl < 4; ++jl) {
            float a0 = ((const float*)&f0)[jl], a1 = ((const float*)&f1)[jl];
            float a2 = ((const float*)&f2)[jl], a3 = ((const float*)&f3)[jl];
            int pk = __builtin_amdgcn_cvt_pk_fp8_f32(a0, a1, 0, false);
            pk     = __builtin_amdgcn_cvt_pk_fp8_f32(a2, a3, pk, true);
            int l = lg * 4 + jl;
            *(int*)(As + l * 256 + (((d0 >> 4) ^ (l & 15)) << 4) + (d0 & 15)) = pk;
        }
    }
#pragma unroll
    for (int m = 1; m < 64; m <<= 1) xs2 += __shfl_xor(xs2, m, 64);
    if (lane == 0) wsumS[wv] = xs2;
    __syncthreads();              // As ready + Bs0 DMA drained

    // ---- A fragments (16 VGPRs): row = wm*16 + l15
    int8v af[2];
    {
        int arow = wm * 16 + l15;
#pragma unroll
        for (int ks = 0; ks < 2; ++ks) {
            int ch = ks * 8 + l4 * 2;
            V8 u;
            u.h[0] = *(const int4v*)(As + arow * 256 + ((ch ^ l15) << 4));
            u.h[1] = *(const int4v*)(As + arow * 256 + (((ch + 1) ^ l15) << 4));
            af[ks] = u.v;
        }
    }

    unsigned int rk[4] = {0u, 0u, 0u, 0u};
    unsigned char* bufs[2] = {Bs0, Bs1};
    for (int cb = 0; cb < 64; ++cb) {
        if (cb < 63) {            // prefetch next 64-col tile
            const unsigned char* g = Wn + (size_t)(cb + 1) * 64 * 256;
            unsigned char* lb = bufs[(cb + 1) & 1];
            async_load16(g + goff[0], lb + loff[0]);
            async_load16(g + goff[1], lb + loff[1]);
        }
        const unsigned char* bb = bufs[cb & 1];
        int8v bf[2][2];
#pragma unroll
        for (int fn = 0; fn < 2; ++fn)
#pragma unroll
            for (int ks = 0; ks < 2; ++ks) {
                int col = wn * 32 + fn * 16 + l15;
                int ch = ks * 8 + l4 * 2;
                V8 u;
                u.h[0] = *(const int4v*)(bb + col * 256 + ((ch ^ l15) << 4));
                u.h[1] = *(const int4v*)(bb + col * 256 + (((ch + 1) ^ l15) << 4));
                bf[fn][ks] = u.v;
            }
        unsigned int i0 = (unsigned)(cb * 64 + wn * 32 + l15);
#pragma unroll
        for (int fn = 0; fn < 2; ++fn) {
            floatx4 a = (floatx4)512.0f;
            a = __builtin_amdgcn_mfma_scale_f32_16x16x128_f8f6f4(
                    af[0], bf[fn][0], a, 0, 0, 0, SCALE1, 0, SCALE1);
            a = __builtin_amdgcn_mfma_scale_f32_16x16x128_f8f6f4(
                    af[1], bf[fn][1], a, 0, 0, 0, SCALE1, 0, SCALE1);
            unsigned int ii = i0 + (unsigned)(fn * 16);
#pragma unroll
            for (int r = 0; r < 4; ++r) {
                unsigned int k0 = (__float_as_uint(a[r]) & 0xFFFFF000u) | ii;
                rk[r] = rk[r] > k0 ? rk[r] : k0;
            }
        }
        __syncthreads();          // guards buffer reuse + drains prefetch DMA
    }

    // ---- epilogue: key-max across 16 col-lanes, then 2 col-halves
#pragma unroll
    for (int r = 0; r < 4; ++r) {
        unsigned int kx = rk[r];
#pragma unroll
        for (int md = 1; md <= 8; md <<= 1) {
            unsigned int o = (unsigned int)__shfl_xor((int)kx, md, 64);
            kx = kx > o ? kx : o;
        }
        if (l15 == 0) red[wm * 16 + l4 * 4 + r][wn] = kx;
    }
    __syncthreads();
    float blockloss = 0.f;
    if (tid < 64) {               // wave 0: merge + hist + closed-form loss
        unsigned int k0 = red[tid][0], k1 = red[tid][1];
        unsigned int kx = k0 > k1 ? k0 : k1;
        int ix = (int)(kx & 0xFFFu);
        kidx[tid] = ix;
        atomicAdd(&counts[ix], 1);
        float v  = __uint_as_float(kx & 0xFFFFF000u) - 512.0f;  // 16*(x.w_hat)
        float nw = wnorm[ix];
        float contr = nw * nw - v * nw * 0.125f;   // ||w||^2 - 2*(v/16)*||w||
#pragma unroll
        for (int m = 1; m < 64; m <<= 1) contr += __shfl_xor(contr, m, 64);
        if (tid == 0) {
            float t = contr;
#pragma unroll
            for (int k = 0; k < 8; ++k) t += wsumS[k];
            blockloss = t;
        }
    }
    __syncthreads();              // kidx visible; counts atomics drained
    if (tid == 0) {
        atomicAdd(lossacc, blockloss);
        __threadfence();
        lastp[0] = (atomicAdd(done, 1) == 511);
    }

    // ---- scatter w[idx] -> out (2 passes x 32 rows via LDS transpose tile)
    int lq = tid & 7, dg = tid >> 3;              // 8 l-quads x 64 d
#pragma unroll
    for (int p = 0; p < 2; ++p) {
#pragma unroll
        for (int j = 0; j < 4; ++j) {             // wave stages 4 rows (1KB each)
            int r = wv * 4 + j;
            float4 vv = *(const float4*)(w + (size_t)kidx[p * 32 + r] * Dd + lane * 4);
            *(float4*)(&wt[r * 260 + lane * 4]) = vv;
        }
        __syncthreads();
#pragma unroll
        for (int jj = 0; jj < 4; ++jj) {
            int d = dg + 64 * jj;
            float4 qv = { wt[(lq * 4 + 0) * 260 + d], wt[(lq * 4 + 1) * 260 + d],
                          wt[(lq * 4 + 2) * 260 + d], wt[(lq * 4 + 3) * 260 + d] };
            *(float4*)(out + ((size_t)b * Dd + d) * Ll + l0 + p * 32 + lq * 4) = qv;
        }
        __syncthreads();          // wt free for next pass / finale
    }

    // ---- finale: last block computes loss + perplexity
    if (lastp[0] && wv == 0) {
        __threadfence();
        float s = 0.f;
        for (int i = lane; i < Kk; i += 64) {
            float pr = (float)counts[i] * (1.0f / Nn);
            s += pr * logf(pr + 1e-10f);
        }
#pragma unroll
        for (int m = 1; m < 64; m <<= 1) s += __shfl_xor(s, m, 64);
        if (lane == 0) {
            out[OUT0]     = lossacc[0] * 1.25f / (float)OUT0;  // q + 0.25*e latent
            out[OUT0 + 1] = expf(-s);
        }
    }
}

// ---------------------------------------------------------------- launch
extern "C" void kernel_launch(void* const* d_in, const int* in_sizes, int n_in,
                              void* d_out, int out_size, void* d_ws, size_t ws_size,
                              hipStream_t stream) {
    const float* x = (const float*)d_in[0];   // [B, D, L]
    const float* w = (const float*)d_in[1];   // [K, D]
    float* out = (float*)d_out;
    char* ws = (char*)d_ws;

    unsigned char* wn    = (unsigned char*)ws;                        // 1 MB fp8
    float*         wnorm = (float*)(ws + (1u << 20));                 // 16 KB
    int*           counts = (int*)(ws + (1u << 20) + (16u << 10));    // 16 KB + 8

    k_prep<<<1024, 256, 0, stream>>>(w, wn, wnorm, counts);
    k_main<<<512,  512, 0, stream>>>(x, wn, wnorm, w, out, counts);
}